// Round 1
// baseline (201.227 us; speedup 1.0000x reference)
//
#include <hip/hip_runtime.h>
#include <hip/hip_bf16.h>

typedef short bf16x8 __attribute__((ext_vector_type(8)));
typedef float f32x4 __attribute__((ext_vector_type(4)));
typedef unsigned short u16;
typedef unsigned int u32;

__device__ __forceinline__ u16 f2b(float v) {
    u32 u = __float_as_uint(v);
    u += 0x7fff + ((u >> 16) & 1);   // round-to-nearest-even
    return (u16)(u >> 16);
}

// ---------------- prep kernels ----------------
__global__ void cast_f32_to_bf16_vec(const float* __restrict__ in, u16* __restrict__ out, int n4) {
    int i = blockIdx.x * blockDim.x + threadIdx.x;
    int stride = gridDim.x * blockDim.x;
    for (; i < n4; i += stride) {
        float4 v = ((const float4*)in)[i];
        ushort4 o;
        o.x = f2b(v.x); o.y = f2b(v.y); o.z = f2b(v.z); o.w = f2b(v.w);
        ((ushort4*)out)[i] = o;
    }
}

// wt[n*K + k] = w[k*N + n]  (f32 -> bf16)
__global__ void cast_transpose(const float* __restrict__ w, u16* __restrict__ wt, int N, int K) {
    int i = blockIdx.x * blockDim.x + threadIdx.x;
    if (i >= N * K) return;
    int n = i / K, k = i - n * K;
    wt[i] = f2b(w[(size_t)k * N + n]);
}

// rpb[h][i][j] = table[rpi[i][j]*6 + h]
__global__ void rpb_gather(const int* __restrict__ rpi, const float* __restrict__ table,
                           float* __restrict__ rpb) {
    int ij = blockIdx.x * blockDim.x + threadIdx.x;  // 65536
    int idx = rpi[ij];
#pragma unroll
    for (int h = 0; h < 6; ++h) rpb[h * 65536 + ij] = table[idx * 6 + h];
}

// ---------------- GEMM: C[M][N] = A[M][192] * Bt[N][192]^T ----------------
// BM=128, BN=64, 4 waves (2x2), wave tile 64x32, full K staged in LDS.
template <bool IS_QKV>
__global__ __launch_bounds__(256) void gemm_k(const u16* __restrict__ A, const u16* __restrict__ Bt,
                                              const float* __restrict__ bias, void* outp, int N,
                                              float qscale) {
    __shared__ u16 lsA[128 * 200];
    __shared__ u16 lsB[64 * 200];
    const int m0 = blockIdx.x * 128;
    const int n0 = blockIdx.y * 64;
    const int tid = threadIdx.x;

    for (int c = tid; c < 128 * 24; c += 256) {
        int r = c / 24, cc = c % 24;
        *(uint4*)&lsA[r * 200 + cc * 8] = *(const uint4*)(A + (size_t)(m0 + r) * 192 + cc * 8);
    }
    for (int c = tid; c < 64 * 24; c += 256) {
        int r = c / 24, cc = c % 24;
        *(uint4*)&lsB[r * 200 + cc * 8] = *(const uint4*)(Bt + (size_t)(n0 + r) * 192 + cc * 8);
    }
    __syncthreads();

    const int l = tid & 63, wv = tid >> 6;
    const int wm = wv >> 1, wn = wv & 1;
    const int lr = l & 15, lg = l >> 4;

    f32x4 acc[4][2] = {};
#pragma unroll
    for (int ks = 0; ks < 6; ++ks) {
        bf16x8 a[4], b[2];
#pragma unroll
        for (int i = 0; i < 4; ++i)
            a[i] = *(const bf16x8*)&lsA[(wm * 64 + i * 16 + lr) * 200 + ks * 32 + lg * 8];
#pragma unroll
        for (int i = 0; i < 2; ++i)
            b[i] = *(const bf16x8*)&lsB[(wn * 32 + i * 16 + lr) * 200 + ks * 32 + lg * 8];
#pragma unroll
        for (int m = 0; m < 4; ++m)
#pragma unroll
            for (int n = 0; n < 2; ++n)
                acc[m][n] = __builtin_amdgcn_mfma_f32_16x16x32_bf16(a[m], b[n], acc[m][n], 0, 0, 0);
    }

#pragma unroll
    for (int m = 0; m < 4; ++m)
#pragma unroll
        for (int n = 0; n < 2; ++n)
#pragma unroll
            for (int j = 0; j < 4; ++j) {
                int gr = m0 + wm * 64 + m * 16 + lg * 4 + j;
                int gc = n0 + wn * 32 + n * 16 + lr;
                float v = acc[m][n][j];
                if (IS_QKV) {
                    if (gc < 192) v *= qscale;
                    v += bias[gc];
                    ((u16*)outp)[(size_t)gr * N + gc] = f2b(v);
                } else {
                    v += bias[gc];
                    ((float*)outp)[(size_t)gr * N + gc] = v;
                }
            }
}

// ---------------- attention ----------------
// block = (window, head, half of 128 q-rows); 8 waves x 16 q-rows.
__global__ __launch_bounds__(512, 2) void attn_k(const u16* __restrict__ qkv,
                                                 const float* __restrict__ rpb,
                                                 const float* __restrict__ mask,
                                                 u16* __restrict__ out) {
    __shared__ u16 lq[128 * 40];    // Q rows (this half), padded stride 40
    __shared__ u16 lk[256 * 40];    // K rows
    __shared__ u16 lvt[32 * 264];   // V transposed [d][np], padded stride 264
    __shared__ u16 lp[8 * 2 * 640]; // per-wave double-buffered P chunk [16][40]

    const int b = blockIdx.x;
    const int w = b / 12;
    const int rem = b % 12;
    const int h = rem >> 1, half = rem & 1;
    const int tid = threadIdx.x;

    // stage Q (128 rows x 32 d, 4 chunks of 8 bf16 per row)
    for (int c = tid; c < 128 * 4; c += 512) {
        int i = c >> 2, cc = c & 3;
        size_t g = ((size_t)(w * 256 + half * 128 + i) * 3 + 0) * 192 + h * 32 + cc * 8;
        *(uint4*)&lq[i * 40 + cc * 8] = *(const uint4*)(qkv + g);
    }
    // stage K (256 rows)
    for (int c = tid; c < 256 * 4; c += 512) {
        int j = c >> 2, cc = c & 3;
        size_t g = ((size_t)(w * 256 + j) * 3 + 1) * 192 + h * 32 + cc * 8;
        *(uint4*)&lk[j * 40 + cc * 8] = *(const uint4*)(qkv + g);
    }
    // stage V transposed: thread t covers j = t/2, d = (t&1)*16 .. +16
    {
        int j = tid >> 1, d0 = (tid & 1) * 16;
        size_t g = ((size_t)(w * 256 + j) * 3 + 2) * 192 + h * 32 + d0;
        union { uint4 u; u16 s[8]; } u0, u1;
        u0.u = *(const uint4*)(qkv + g);
        u1.u = *(const uint4*)(qkv + g + 8);
#pragma unroll
        for (int dd = 0; dd < 8; ++dd) {
            lvt[(d0 + dd) * 264 + j] = u0.s[dd];
            lvt[(d0 + 8 + dd) * 264 + j] = u1.s[dd];
        }
    }
    __syncthreads();

    const int l = tid & 63, wv = tid >> 6;
    const int lr = l & 15, lg = l >> 4;
    const f32x4 zero = {0.f, 0.f, 0.f, 0.f};

    // S = Q Kt : one A-frag (16 rows x k32), 16 B-frags over the 256 kv cols
    f32x4 s[16];
    bf16x8 aq = *(const bf16x8*)&lq[(wv * 16 + lr) * 40 + lg * 8];
#pragma unroll
    for (int nt = 0; nt < 16; ++nt) {
        bf16x8 bk = *(const bf16x8*)&lk[(nt * 16 + lr) * 40 + lg * 8];
        s[nt] = __builtin_amdgcn_mfma_f32_16x16x32_bf16(aq, bk, zero, 0, 0, 0);
    }

    // add rpb + mask, row softmax (rows = lg*4 + j, cols = nt*16 + lr)
    float rsum[4];
    const float* mbase = mask + (size_t)w * 65536;
    const float* bbase = rpb + (size_t)h * 65536;
#pragma unroll
    for (int j = 0; j < 4; ++j) {
        int i = half * 128 + wv * 16 + lg * 4 + j;
        const float* mr = mbase + i * 256;
        const float* br = bbase + i * 256;
        float mx = -1e30f;
#pragma unroll
        for (int nt = 0; nt < 16; ++nt) {
            float v = s[nt][j] + mr[nt * 16 + lr] + br[nt * 16 + lr];
            s[nt][j] = v;
            mx = fmaxf(mx, v);
        }
#pragma unroll
        for (int off = 1; off < 16; off <<= 1) mx = fmaxf(mx, __shfl_xor(mx, off));
        float sum = 0.f;
#pragma unroll
        for (int nt = 0; nt < 16; ++nt) {
            float e = __expf(s[nt][j] - mx);
            s[nt][j] = e;
            sum += e;
        }
#pragma unroll
        for (int off = 1; off < 16; off <<= 1) sum += __shfl_xor(sum, off);
        rsum[j] = sum;
    }

    // O = P V, processing kv in chunks of 32 via wave-private LDS transpose of P
    f32x4 o[2] = {};
    u16* pw = lp + wv * 2 * 640;
#pragma unroll
    for (int c = 0; c < 8; ++c) {
        u16* pb = pw + (c & 1) * 640;
#pragma unroll
        for (int t = 0; t < 2; ++t) {
            int nt = 2 * c + t;
#pragma unroll
            for (int j = 0; j < 4; ++j)
                pb[(lg * 4 + j) * 40 + t * 16 + lr] = f2b(s[nt][j]);
        }
        bf16x8 ap = *(const bf16x8*)&pb[lr * 40 + lg * 8];
#pragma unroll
        for (int dt = 0; dt < 2; ++dt) {
            bf16x8 bv = *(const bf16x8*)&lvt[(dt * 16 + lr) * 264 + c * 32 + lg * 8];
            o[dt] = __builtin_amdgcn_mfma_f32_16x16x32_bf16(ap, bv, o[dt], 0, 0, 0);
        }
    }

    // normalize + store to [w][i][h*32+d] bf16
#pragma unroll
    for (int dt = 0; dt < 2; ++dt)
#pragma unroll
        for (int j = 0; j < 4; ++j) {
            int i = half * 128 + wv * 16 + lg * 4 + j;
            float v = o[dt][j] / rsum[j];
            out[((size_t)(w * 256 + i)) * 192 + h * 32 + dt * 16 + lr] = f2b(v);
        }
}

extern "C" void kernel_launch(void* const* d_in, const int* in_sizes, int n_in,
                              void* d_out, int out_size, void* d_ws, size_t ws_size,
                              hipStream_t stream) {
    const float* x      = (const float*)d_in[0];
    const int*   rpi    = (const int*)d_in[1];
    const float* mask   = (const float*)d_in[2];
    const float* qkv_w  = (const float*)d_in[3];
    const float* qkv_b  = (const float*)d_in[4];
    const float* proj_w = (const float*)d_in[5];
    const float* proj_b = (const float*)d_in[6];
    const float* table  = (const float*)d_in[7];

    char* p = (char*)d_ws;
    u16* xb   = (u16*)p;  p += (size_t)65536 * 192 * 2;  // x bf16; later reused as attn_out
    u16* qkvb = (u16*)p;  p += (size_t)65536 * 576 * 2;  // qkv bf16 [w][i][3][h][d]
    u16* wtq  = (u16*)p;  p += (size_t)576 * 192 * 2;    // qkv_w^T bf16 [576][192]
    u16* wtp  = (u16*)p;  p += (size_t)192 * 192 * 2;    // proj_w^T bf16 [192][192]
    float* rpb = (float*)p; p += (size_t)6 * 65536 * 4;  // [6][256][256]

    hipLaunchKernelGGL(cast_f32_to_bf16_vec, dim3(2048), dim3(256), 0, stream,
                       x, xb, 65536 * 192 / 4);
    hipLaunchKernelGGL(cast_transpose, dim3((576 * 192 + 255) / 256), dim3(256), 0, stream,
                       qkv_w, wtq, 576, 192);
    hipLaunchKernelGGL(cast_transpose, dim3((192 * 192 + 255) / 256), dim3(256), 0, stream,
                       proj_w, wtp, 192, 192);
    hipLaunchKernelGGL(rpb_gather, dim3(256), dim3(256), 0, stream, rpi, table, rpb);

    const float qscale = 0.17677669529663687f;  // 1/sqrt(32)
    hipLaunchKernelGGL((gemm_k<true>), dim3(512, 9), dim3(256), 0, stream,
                       xb, wtq, qkv_b, (void*)qkvb, 576, qscale);
    hipLaunchKernelGGL(attn_k, dim3(3072), dim3(512), 0, stream, qkvb, rpb, mask, xb);
    hipLaunchKernelGGL((gemm_k<false>), dim3(512, 3), dim3(256), 0, stream,
                       xb, wtp, proj_b, d_out, 192, 1.0f);
}